// Round 9
// baseline (90.587 us; speedup 1.0000x reference)
//
#include <hip/hip_runtime.h>
#include <hip/hip_bf16.h>

// Problem constants
#define SRC    16384     // 128*128 source pixels
#define DCH    64        // channels
#define NCLS   19        // classes
#define NPAIR  (NCLS*DCH)// 1216 (c,d) pairs

// Bare v_exp_f32 (args in [-450,0]; underflow->0 matches reference f32 exp).
#if defined(__has_builtin)
#if __has_builtin(__builtin_amdgcn_exp2f)
#define EXP2F(x) __builtin_amdgcn_exp2f(x)
#else
#define EXP2F(x) __exp2f(x)
#endif
#else
#define EXP2F(x) __exp2f(x)
#endif

// ---------------------------------------------------------------------------
// K1: per-source-pixel class counts. Each source pixel covers a 4x4 block of
// the 512x512 label map. cnt[c*SRC + s] = #subpixels with label c (0..16).
// Also zeroes the psum accumulator (K2 atomicAdds into it after the boundary).
// ---------------------------------------------------------------------------
__global__ __launch_bounds__(256) void hl_count_kernel(
    const int* __restrict__ label, unsigned char* __restrict__ cnt,
    float* __restrict__ psum)
{
    if (blockIdx.x == 0 && threadIdx.x == 0) psum[0] = 0.f;
    int s  = blockIdx.x * 256 + threadIdx.x;   // 64 blocks x 256 = 16384
    int sy = s >> 7, sx = s & 127;
    const int4* lab4 = (const int4*)label;
    int l[16];
#pragma unroll
    for (int r = 0; r < 4; r++) {
        int4 v = lab4[(4 * sy + r) * 128 + sx];
        l[4 * r + 0] = v.x; l[4 * r + 1] = v.y;
        l[4 * r + 2] = v.z; l[4 * r + 3] = v.w;
    }
#pragma unroll
    for (int c = 0; c < NCLS; c++) {
        int cc = 0;
#pragma unroll
        for (int j = 0; j < 16; j++) cc += (l[j] == c) ? 1 : 0;
        cnt[c * SRC + s] = (unsigned char)cc;
    }
}

// ---------------------------------------------------------------------------
// K2: fused moments + KDE + per-pair loss. One 256-thread block per (c,d),
// 64 px/thread. Key insight: mu/var/n of pair (c,d) depend ONLY on this
// block's own 80 KB (feature row d + cnt row c) -> no grid-wide dependency,
// no moments kernel, no S1/S2 round-trip.
//   Pass 1: f32 thread partials -> f64 shuffle/LDS reduce -> mu, istd, n.
//           d==0 block publishes ncls[c] (plain store; read only by K3).
//   Pass 2: 7-bin KDE (bare v_exp_f32; 1/sqrt(2*pi*var_s) cancels in the
//           normalization), block reduce, smooth-L1 vs fixed target, one
//           f32 atomicAdd of the raw partial into psum (order noise ~1e-9).
// launch_bounds(256,8) caps VGPRs at 64 -> all 4864 waves co-resident.
// ---------------------------------------------------------------------------
__global__ __launch_bounds__(256, 8) void hl_fused_kernel(
    const float* __restrict__ feature, const unsigned char* __restrict__ cnt,
    int* __restrict__ ncls, float* __restrict__ psum)
{
    int w = blockIdx.x;             // pair 0..1215
    int c = w >> 6, d = w & 63;
    int t = threadIdx.x;
    int wid = t >> 6;

    const float4*       fp4 = (const float4*)(feature + d * SRC);
    const unsigned int* cpu = (const unsigned int*)(cnt + c * SRC);

    // ---- Pass 1: moments --------------------------------------------------
    float f1 = 0.f, f2 = 0.f;
    int   nc = 0;
#pragma unroll 4
    for (int i = 0; i < 16; i++) {
        int g = i * 256 + t;        // 4096 float4-groups (= 4096 uint groups)
        float4       x  = fp4[g];
        unsigned int cv = cpu[g];
        float xs[4] = {x.x, x.y, x.z, x.w};
        float cf[4] = {(float)(cv & 255u), (float)((cv >> 8) & 255u),
                       (float)((cv >> 16) & 255u), (float)(cv >> 24)};
#pragma unroll
        for (int e = 0; e < 4; e++) {
            float wx = cf[e] * xs[e];
            f1 += wx;
            f2 = fmaf(wx, xs[e], f2);
        }
        nc += (cv & 255u) + ((cv >> 8) & 255u) + ((cv >> 16) & 255u) + (cv >> 24);
    }
    double s1 = (double)f1, s2 = (double)f2;
#pragma unroll
    for (int o = 32; o > 0; o >>= 1) {
        s1 += __shfl_down(s1, o);
        s2 += __shfl_down(s2, o);
        nc += __shfl_down(nc, o);
    }
    __shared__ double ps1[4], ps2[4];
    __shared__ int    pn[4];
    __shared__ float  sh_mu, sh_istd;
    __shared__ int    sh_act;
    if ((t & 63) == 0) { ps1[wid] = s1; ps2[wid] = s2; pn[wid] = nc; }
    __syncthreads();
    if (t == 0) {
        double a = ps1[0] + ps1[1] + ps1[2] + ps1[3];
        double b = ps2[0] + ps2[1] + ps2[2] + ps2[3];
        int    n = pn[0] + pn[1] + pn[2] + pn[3];
        double nsafe = (n > 0) ? (double)n : 1.0;
        double mu  = a / nsafe;
        double var = (b - 2.0 * mu * a + mu * mu * (double)n) / nsafe + 1e-10;
        sh_mu   = (float)mu;
        sh_istd = (float)(1.0 / sqrt(var));
        sh_act  = (n >= 1000);
        if (d == 0) ncls[c] = n;    // plain store; consumed only by K3
    }
    __syncthreads();
    if (!sh_act) return;            // inactive class: contributes 0
    float istd = sh_istd;
    float nm   = -sh_mu * istd;     // u = fma(x, istd, nm)

    // ---- Pass 2: KDE (data is L1/L2-hot from pass 1) ----------------------
    const float C1 = -18.033688011112042f;   // -12.5 * log2(e)
    float acc[7] = {0.f, 0.f, 0.f, 0.f, 0.f, 0.f, 0.f};

#pragma unroll 2
    for (int i = 0; i < 16; i++) {
        int g = i * 256 + t;
        float4       x  = fp4[g];
        unsigned int cv = cpu[g];
        float xs[4] = {x.x, x.y, x.z, x.w};
        float cf[4] = {(float)(cv & 255u), (float)((cv >> 8) & 255u),
                       (float)((cv >> 16) & 255u), (float)(cv >> 24)};
#pragma unroll
        for (int e = 0; e < 4; e++) {
            float u = fmaf(xs[e], istd, nm);
            float p = C1 * u;
            float q = p * u;                 // C1*u^2
#pragma unroll
            for (int k = 0; k < 7; k++) {
                float km  = (float)(k - 3);
                float arg = fmaf(p, -2.f * km, q + C1 * km * km);
                acc[k] = fmaf(cf[e], EXP2F(arg), acc[k]);
            }
        }
    }

    __shared__ float part[4][7];
#pragma unroll
    for (int j = 0; j < 7; j++) {
        float v = acc[j];
#pragma unroll
        for (int o = 32; o > 0; o >>= 1) v += __shfl_down(v, o);
        if ((t & 63) == 0) part[wid][j] = v;
    }
    __syncthreads();

    if (t == 0) {
        // target: exp(-0.5 k^2)/Z (1/sqrt(2 pi var) cancels in normalization)
        double e[7], z = 0.0;
#pragma unroll
        for (int k = -3; k <= 3; k++) { e[k + 3] = exp(-0.5 * (double)(k * k)); z += e[k + 3]; }

        float hist[7], S = 0.f;
#pragma unroll
        for (int j = 0; j < 7; j++) {
            hist[j] = part[0][j] + part[1][j] + part[2][j] + part[3][j];
            S += hist[j];
        }
        float Ss = fmaxf(S, 1e-30f);
        float ps = 0.f;
#pragma unroll
        for (int j = 0; j < 7; j++) {
            float dd = fabsf(hist[j] / Ss - (float)(e[j] / z));
            ps += (dd < 1.f) ? 0.5f * dd * dd : (dd - 0.5f);
        }
        atomicAdd(psum, ps);        // raw partial; scaled once in K3
    }
}

// ---------------------------------------------------------------------------
// K3: finalize. A = #active classes; out = psum / (448 * A). Writes out
// absolutely (harness-poisoned d_out needs no pre-zero).
// ---------------------------------------------------------------------------
__global__ __launch_bounds__(64) void hl_final_kernel(
    const float* __restrict__ psum, const int* __restrict__ ncls,
    float* __restrict__ out)
{
    if (threadIdx.x == 0) {
        int A = 0;
#pragma unroll
        for (int i = 0; i < NCLS; i++) A += (ncls[i] >= 1000) ? 1 : 0;
        out[0] = (A > 0) ? psum[0] / (448.0f * (float)A) : 0.0f;
    }
}

// ---------------------------------------------------------------------------
extern "C" void kernel_launch(void* const* d_in, const int* in_sizes, int n_in,
                              void* d_out, int out_size, void* d_ws, size_t ws_size,
                              hipStream_t stream)
{
    const float* feature = (const float*)d_in[0];   // [1,64,128,128] fp32
    const int*   label   = (const int*)d_in[1];     // [1,1,512,512]  int32
    float*       out     = (float*)d_out;           // scalar fp32

    char* ws = (char*)d_ws;
    unsigned char* cnt  = (unsigned char*)(ws);      // 311296 B
    int*           ncls = (int*)(ws + 311296);       // 76 B
    float*         psum = (float*)(ws + 311424);     // 4 B

    hl_count_kernel<<<SRC / 256, 256, 0, stream>>>(label, cnt, psum);
    hl_fused_kernel<<<NPAIR, 256, 0, stream>>>(feature, cnt, ncls, psum);
    hl_final_kernel<<<1, 64, 0, stream>>>(psum, ncls, out);
}

// Round 10
// 88.303 us; speedup vs baseline: 1.0259x; 1.0259x over previous
//
#include <hip/hip_runtime.h>
#include <hip/hip_bf16.h>

// Problem constants
#define SRC    16384     // 128*128 source pixels
#define DCH    64        // channels
#define NCLS   19        // classes
#define NPAIR  (NCLS*DCH)// 1216 (c,d) pairs

// Bare v_exp_f32 (args in [-450,0]; underflow->0 matches reference f32 exp).
#if defined(__has_builtin)
#if __has_builtin(__builtin_amdgcn_exp2f)
#define EXP2F(x) __builtin_amdgcn_exp2f(x)
#else
#define EXP2F(x) __exp2f(x)
#endif
#else
#define EXP2F(x) __exp2f(x)
#endif

// ---------------------------------------------------------------------------
// K1: per-source-pixel class counts. Each source pixel covers a 4x4 block of
// the 512x512 label map. cnt[c*SRC + s] = #subpixels with label c (0..16).
// Also zeroes the psum accumulator (K2 atomicAdds into it after the boundary).
// ---------------------------------------------------------------------------
__global__ __launch_bounds__(256) void hl_count_kernel(
    const int* __restrict__ label, unsigned char* __restrict__ cnt,
    float* __restrict__ psum)
{
    if (blockIdx.x == 0 && threadIdx.x == 0) psum[0] = 0.f;
    int s  = blockIdx.x * 256 + threadIdx.x;   // 64 blocks x 256 = 16384
    int sy = s >> 7, sx = s & 127;
    const int4* lab4 = (const int4*)label;
    int l[16];
#pragma unroll
    for (int r = 0; r < 4; r++) {
        int4 v = lab4[(4 * sy + r) * 128 + sx];
        l[4 * r + 0] = v.x; l[4 * r + 1] = v.y;
        l[4 * r + 2] = v.z; l[4 * r + 3] = v.w;
    }
#pragma unroll
    for (int c = 0; c < NCLS; c++) {
        int cc = 0;
#pragma unroll
        for (int j = 0; j < 16; j++) cc += (l[j] == c) ? 1 : 0;
        cnt[c * SRC + s] = (unsigned char)cc;
    }
}

// ---------------------------------------------------------------------------
// K2: fused moments + KDE + per-pair loss. One 256-thread block per (c,d),
// 64 px/thread. mu/var/n of pair (c,d) depend only on this block's own 80 KB
// (feature row d + cnt row c) -> no grid-wide dependency.
//   Pass 1: f32 thread partials -> f64 shuffle/LDS reduce -> mu, istd, n.
//           d==0 block publishes ncls[c] (plain store; read only by K3).
//   Pass 2: 7-bin KDE (bare v_exp_f32; 1/sqrt(2*pi*var_s) cancels in the
//           normalization), block reduce, smooth-L1 vs fixed target, one
//           f32 atomicAdd of the raw partial into psum (order noise ~1e-9).
// launch_bounds(256,4): 128-VGPR budget -> NO spills (the (256,8)/64-reg cap
// was the R8/R9 suspect); 4 blocks/CU = 16 waves/CU is ample latency hiding
// for this compute-dense loop (per-iter compute ~750 cy >> L2 ~200 cy).
// ---------------------------------------------------------------------------
__global__ __launch_bounds__(256, 4) void hl_fused_kernel(
    const float* __restrict__ feature, const unsigned char* __restrict__ cnt,
    int* __restrict__ ncls, float* __restrict__ psum)
{
    int w = blockIdx.x;             // pair 0..1215
    int c = w >> 6, d = w & 63;
    int t = threadIdx.x;
    int wid = t >> 6;

    const float4*       fp4 = (const float4*)(feature + d * SRC);
    const unsigned int* cpu = (const unsigned int*)(cnt + c * SRC);

    // ---- Pass 1: moments --------------------------------------------------
    float f1 = 0.f, f2 = 0.f;
    int   nc = 0;
#pragma unroll 4
    for (int i = 0; i < 16; i++) {
        int g = i * 256 + t;        // 4096 float4-groups (= 4096 uint groups)
        float4       x  = fp4[g];
        unsigned int cv = cpu[g];
        float xs[4] = {x.x, x.y, x.z, x.w};
        float cf[4] = {(float)(cv & 255u), (float)((cv >> 8) & 255u),
                       (float)((cv >> 16) & 255u), (float)(cv >> 24)};
#pragma unroll
        for (int e = 0; e < 4; e++) {
            float wx = cf[e] * xs[e];
            f1 += wx;
            f2 = fmaf(wx, xs[e], f2);
        }
        nc += (cv & 255u) + ((cv >> 8) & 255u) + ((cv >> 16) & 255u) + (cv >> 24);
    }
    double s1 = (double)f1, s2 = (double)f2;
#pragma unroll
    for (int o = 32; o > 0; o >>= 1) {
        s1 += __shfl_down(s1, o);
        s2 += __shfl_down(s2, o);
        nc += __shfl_down(nc, o);
    }
    __shared__ double ps1[4], ps2[4];
    __shared__ int    pn[4];
    __shared__ float  sh_mu, sh_istd;
    __shared__ int    sh_act;
    if ((t & 63) == 0) { ps1[wid] = s1; ps2[wid] = s2; pn[wid] = nc; }
    __syncthreads();
    if (t == 0) {
        double a = ps1[0] + ps1[1] + ps1[2] + ps1[3];
        double b = ps2[0] + ps2[1] + ps2[2] + ps2[3];
        int    n = pn[0] + pn[1] + pn[2] + pn[3];
        double nsafe = (n > 0) ? (double)n : 1.0;
        double mu  = a / nsafe;
        double var = (b - 2.0 * mu * a + mu * mu * (double)n) / nsafe + 1e-10;
        sh_mu   = (float)mu;
        sh_istd = (float)(1.0 / sqrt(var));
        sh_act  = (n >= 1000);
        if (d == 0) ncls[c] = n;    // plain store; consumed only by K3
    }
    __syncthreads();
    if (!sh_act) return;            // inactive class: contributes 0
    float istd = sh_istd;
    float nm   = -sh_mu * istd;     // u = fma(x, istd, nm)

    // ---- Pass 2: KDE (data is L1/L2-hot from pass 1) ----------------------
    const float C1 = -18.033688011112042f;   // -12.5 * log2(e)
    float acc[7] = {0.f, 0.f, 0.f, 0.f, 0.f, 0.f, 0.f};

#pragma unroll 2
    for (int i = 0; i < 16; i++) {
        int g = i * 256 + t;
        float4       x  = fp4[g];
        unsigned int cv = cpu[g];
        float xs[4] = {x.x, x.y, x.z, x.w};
        float cf[4] = {(float)(cv & 255u), (float)((cv >> 8) & 255u),
                       (float)((cv >> 16) & 255u), (float)(cv >> 24)};
#pragma unroll
        for (int e = 0; e < 4; e++) {
            float u = fmaf(xs[e], istd, nm);
            float p = C1 * u;
            float q = p * u;                 // C1*u^2
#pragma unroll
            for (int k = 0; k < 7; k++) {
                float km  = (float)(k - 3);
                float arg = fmaf(p, -2.f * km, q + C1 * km * km);
                acc[k] = fmaf(cf[e], EXP2F(arg), acc[k]);
            }
        }
    }

    __shared__ float part[4][7];
#pragma unroll
    for (int j = 0; j < 7; j++) {
        float v = acc[j];
#pragma unroll
        for (int o = 32; o > 0; o >>= 1) v += __shfl_down(v, o);
        if ((t & 63) == 0) part[wid][j] = v;
    }
    __syncthreads();

    if (t == 0) {
        // target: exp(-0.5 k^2)/Z (1/sqrt(2 pi var) cancels in normalization)
        double e[7], z = 0.0;
#pragma unroll
        for (int k = -3; k <= 3; k++) { e[k + 3] = exp(-0.5 * (double)(k * k)); z += e[k + 3]; }

        float hist[7], S = 0.f;
#pragma unroll
        for (int j = 0; j < 7; j++) {
            hist[j] = part[0][j] + part[1][j] + part[2][j] + part[3][j];
            S += hist[j];
        }
        float Ss = fmaxf(S, 1e-30f);
        float ps = 0.f;
#pragma unroll
        for (int j = 0; j < 7; j++) {
            float dd = fabsf(hist[j] / Ss - (float)(e[j] / z));
            ps += (dd < 1.f) ? 0.5f * dd * dd : (dd - 0.5f);
        }
        atomicAdd(psum, ps);        // raw partial; scaled once in K3
    }
}

// ---------------------------------------------------------------------------
// K3: finalize. A = #active classes; out = psum / (448 * A). Writes out
// absolutely (harness-poisoned d_out needs no pre-zero).
// ---------------------------------------------------------------------------
__global__ __launch_bounds__(64) void hl_final_kernel(
    const float* __restrict__ psum, const int* __restrict__ ncls,
    float* __restrict__ out)
{
    if (threadIdx.x == 0) {
        int A = 0;
#pragma unroll
        for (int i = 0; i < NCLS; i++) A += (ncls[i] >= 1000) ? 1 : 0;
        out[0] = (A > 0) ? psum[0] / (448.0f * (float)A) : 0.0f;
    }
}

// ---------------------------------------------------------------------------
extern "C" void kernel_launch(void* const* d_in, const int* in_sizes, int n_in,
                              void* d_out, int out_size, void* d_ws, size_t ws_size,
                              hipStream_t stream)
{
    const float* feature = (const float*)d_in[0];   // [1,64,128,128] fp32
    const int*   label   = (const int*)d_in[1];     // [1,1,512,512]  int32
    float*       out     = (float*)d_out;           // scalar fp32

    char* ws = (char*)d_ws;
    unsigned char* cnt  = (unsigned char*)(ws);      // 311296 B
    int*           ncls = (int*)(ws + 311296);       // 76 B
    float*         psum = (float*)(ws + 311424);     // 4 B

    hl_count_kernel<<<SRC / 256, 256, 0, stream>>>(label, cnt, psum);
    hl_fused_kernel<<<NPAIR, 256, 0, stream>>>(feature, cnt, ncls, psum);
    hl_final_kernel<<<1, 64, 0, stream>>>(psum, ncls, out);
}